// Round 12
// baseline (64.563 us; speedup 1.0000x reference)
//
#include <hip/hip_runtime.h>
#include <hip/hip_bf16.h>
#include <math.h>

#define KS 3
#define C_IN 64
#define F_OUT 128
#define NPOS 9
#define HH 128
#define WWID 128
#define NB 16

typedef __attribute__((ext_vector_type(8))) short bf16x8;
typedef __attribute__((ext_vector_type(4))) float f32x4;

__device__ __forceinline__ unsigned short f2bf(float f) {
  union { float f; unsigned u; } v; v.f = f;
  unsigned u = v.u;
  return (unsigned short)((u + 0x7FFFu + ((u >> 16) & 1u)) >> 16);  // RNE
}
__device__ __forceinline__ unsigned cvtpk(float lo, float hi) {
  unsigned r;
  asm("v_cvt_pk_bf16_f32 %0, %1, %2" : "=v"(r) : "v"(lo), "v"(hi));
  return r;
}
__device__ __forceinline__ bf16x8 pack8(float4 v0, float4 v1) {
  union { unsigned u[4]; bf16x8 v; } r;
  r.u[0] = cvtpk(v0.x, v0.y); r.u[1] = cvtpk(v0.z, v0.w);
  r.u[2] = cvtpk(v1.x, v1.y); r.u[3] = cvtpk(v1.z, v1.w);
  return r.v;
}
__device__ __forceinline__ void gload16(const void* g, void* l) {
  __builtin_amdgcn_global_load_lds(
      (const __attribute__((address_space(1))) unsigned int*)g,
      (__attribute__((address_space(3))) unsigned int*)l, 16, 0, 0);
}

// ---- Kernel 1: AW (bf16 in {-1,0,1}) sliced by kernel-row i (= p/3):
// slice s = positions 3s..3s+2, all 128 f, all 64 ch (48 KiB each), LINEAR.
// elem off = s*24576 + ((pl*128+f)*8 + (g^(f&7)))*8 + (c&7).  (r10-verified)
__global__ void compute_aw(const float* __restrict__ kern,
                           const float* __restrict__ D,
                           const float* __restrict__ gu,
                           unsigned short* __restrict__ AWsw) {
  int t = blockIdx.x * blockDim.x + threadIdx.x;
  if (t >= F_OUT * C_IN) return;
  int base = t * NPOS;
  float pert[NPOS];
#pragma unroll
  for (int n = 0; n < NPOS; ++n) {
    float u = gu[base + n];
    float g = -0.001f * logf(-logf(u + 1e-20f) + 1e-20f);
    pert[n] = D[base + n] + g;
  }
  unsigned mask = 0;
#pragma unroll
  for (int k = 0; k < 4; ++k) {
    int best = 0; float bv = -INFINITY;
#pragma unroll
    for (int n = 0; n < NPOS; ++n) {
      bool taken = (mask >> n) & 1;
      if (!taken && pert[n] > bv) { bv = pert[n]; best = n; }
    }
    mask |= (1u << best);
  }
#pragma unroll
  for (int n = 0; n < NPOS; ++n) {
    int L = base + n;
    float kv = kern[L];
    float sg = (kv > 0.f) ? 1.f : ((kv < 0.f) ? -1.f : 0.f);
    float v = ((mask >> n) & 1) ? sg : 0.f;
    int f = L & (F_OUT - 1);
    int r = L >> 7;
    int c = r & (C_IN - 1);
    int p = r >> 6;
    int s = p / 3, pl = p % 3;
    int g = c >> 3;
    int off = s * 24576 + ((pl * F_OUT + f) * 8 + (g ^ (f & 7))) * 8 + (c & 7);
    AWsw[off] = f2bf(v);
  }
}

// ---- Kernel 2: persistent-strip pipelined conv. 256 blocks (1/CU), 512 thr
// / 8 waves; block marches 8 rows in 2 steps of 4 (r10 wave tile 64x128).
// As = 6-slot LDS row ring; step-1 rows loaded into 32 parked regs during
// step-0 compute (T14), written into freed ring slots. Bs = r10 3-slice
// rotation (reg-prefetch). All swizzles identical to r10 (verified).
__global__ __launch_bounds__(512, 2)
void conv7(const float* __restrict__ x,
           const unsigned short* __restrict__ AWsw,
           const float* __restrict__ bias,
           float* __restrict__ out) {
  __shared__ __align__(16) unsigned short As[6 * 130 * 64];   // 99840 B
  __shared__ __align__(16) unsigned short Bs[3 * F_OUT * 64]; // 49152 B

  int tid = threadIdx.x;
  int lane = tid & 63, wave = tid >> 6;
  int lr = lane & 15, lg = lane >> 4;

  int bid = blockIdx.x;
  int wg = (bid & 7) * 32 + (bid >> 3);   // XCD-contiguous (256 % 8 == 0)
  int n = wg >> 4;
  int h0 = (wg & 15) * 8;

  int ro = wave >> 1;          // row-slot within step (0..3)
  int m0 = (wave & 1) * 64;    // px half

  const float* xim = x + ((long long)n * HH) * WWID * C_IN;

  // ---- pads pp=0 / pp=129 of all 6 slots: zero once (never rewritten).
  bf16x8 z = {};
  if (tid < 96) {
    int r = tid >> 4, k = tid & 15;
    int pp = (k >> 3) ? 129 : 0, c8 = k & 7;
    *reinterpret_cast<bf16x8*>((char*)As + r * 16640 + pp * 128 +
                               ((c8 ^ (pp & 7)) << 4)) = z;
  }

  // ---- B0 via gload_lds (48 wave-issues; drain at bar1)
#pragma unroll
  for (int k = 0; k < 6; ++k) {
    int wi = wave * 6 + k;
    gload16(AWsw + wi * 512 + lane * 8, (char*)Bs + wi * 1024);
  }

  // ---- prologue A: rows h0-1 .. h0+4 into slots 0..5 (clamp + zero-select)
#pragma unroll
  for (int t = 0; t < 12; ++t) {
    int cid = t * 512 + tid;
    int r = cid >> 10, rem = cid & 1023;
    int px = rem >> 3, c8 = rem & 7;
    int hh = h0 - 1 + r;
    int hc = hh < 0 ? 0 : (hh > 127 ? 127 : hh);
    const float* sp = xim + (long long)hc * (WWID * C_IN) + px * C_IN + c8 * 8;
    float4 v0 = *reinterpret_cast<const float4*>(sp);
    float4 v1 = *reinterpret_cast<const float4*>(sp + 4);
    bf16x8 val = ((unsigned)hh < (unsigned)HH) ? pack8(v0, v1) : z;
    int pp = px + 1;
    *reinterpret_cast<bf16x8*>((char*)As + r * 16640 + pp * 128 +
                               ((c8 ^ (pp & 7)) << 4)) = val;
  }
  __syncthreads();

  f32x4 acc[4][8] = {};
  bf16x8 pre[6];
  float4 xv[8];                 // parked next-rows batch (2 rows, 32 regs)

#define PREFETCH(SN)                                                         \
  _Pragma("unroll")                                                          \
  for (int k = 0; k < 6; ++k)                                                \
    pre[k] = *reinterpret_cast<const bf16x8*>(                               \
        AWsw + (SN) * 24576 + (k * 512 + tid) * 8);

#define BWRITE()                                                             \
  _Pragma("unroll")                                                          \
  for (int k = 0; k < 6; ++k)                                                \
    *reinterpret_cast<bf16x8*>(Bs + (k * 512 + tid) * 8) = pre[k];

  // issue 2 rows (h0+5+2*B, h0+6+2*B) into xv (clamped addresses)
#define ISSUE_X(B)                                                           \
  _Pragma("unroll")                                                          \
  for (int c = 0; c < 4; ++c) {                                              \
    int cid = c * 512 + tid;                                                 \
    int rr = cid >> 10, rem = cid & 1023;                                    \
    int px = rem >> 3, c8 = rem & 7;                                         \
    int row = h0 + 5 + 2 * (B) + rr;                                         \
    int hc = row > 127 ? 127 : row;                                          \
    const float* sp = xim + (long long)hc * (WWID * C_IN) + px * C_IN + c8 * 8;\
    xv[c * 2]     = *reinterpret_cast<const float4*>(sp);                    \
    xv[c * 2 + 1] = *reinterpret_cast<const float4*>(sp + 4);                \
  }

  // cvt + write parked batch into ring slots 2B, 2B+1 (zero if OOB row)
#define DRAIN_X(B)                                                           \
  _Pragma("unroll")                                                          \
  for (int c = 0; c < 4; ++c) {                                              \
    int cid = c * 512 + tid;                                                 \
    int rr = cid >> 10, rem = cid & 1023;                                    \
    int px = rem >> 3, c8 = rem & 7;                                         \
    int row = h0 + 5 + 2 * (B) + rr;                                         \
    bf16x8 val = (row < HH) ? pack8(xv[c * 2], xv[c * 2 + 1]) : z;           \
    int sl = 2 * (B) + rr;                                                   \
    int pp = px + 1;                                                         \
    *reinterpret_cast<bf16x8*>((char*)As + sl * 16640 + pp * 128 +           \
                               ((c8 ^ (pp & 7)) << 4)) = val;                \
  }

  // one phase: kernel-row S of step T; A row-slot = (ro + S + 4T) mod 6
#define COMPUTE(T, S)                                                        \
  {                                                                          \
    int sl = ro + (S) + 4 * (T);                                             \
    if (sl >= 6) sl -= 6;                                                    \
    const char* arow = (const char*)As + sl * 16640;                         \
    __builtin_amdgcn_s_setprio(1);                                           \
    _Pragma("unroll")                                                        \
    for (int ch = 0; ch < 2; ++ch) {                                         \
      const int pl = (S);                                                    \
      (void)pl;                                                              \
      _Pragma("unroll")                                                      \
      for (int j = 0; j < 3; ++j) {                                          \
        const char* bp = (const char*)Bs + j * 16384 + lr * 128 +            \
                         (((ch * 4 + lg) ^ (lr & 7)) << 4);                  \
        bf16x8 b[8];                                                         \
        _Pragma("unroll")                                                    \
        for (int nf = 0; nf < 8; ++nf)                                       \
          b[nf] = *reinterpret_cast<const bf16x8*>(bp + nf * 2048);          \
        bf16x8 a[4];                                                         \
        _Pragma("unroll")                                                    \
        for (int mfi = 0; mfi < 4; ++mfi) {                                  \
          int pxb = m0 + mfi * 16 + lr + j;                                  \
          a[mfi] = *reinterpret_cast<const bf16x8*>(                         \
              arow + pxb * 128 + (((ch * 4 + lg) ^ (pxb & 7)) << 4));        \
        }                                                                    \
        _Pragma("unroll")                                                    \
        for (int mfi = 0; mfi < 4; ++mfi)                                    \
          _Pragma("unroll")                                                  \
          for (int nf = 0; nf < 8; ++nf)                                     \
            acc[mfi][nf] = __builtin_amdgcn_mfma_f32_16x16x32_bf16(          \
                a[mfi], b[nf], acc[mfi][nf], 0, 0, 0);                       \
      }                                                                      \
    }                                                                        \
    __builtin_amdgcn_s_setprio(0);                                           \
  }

#define EPILOGUE(T)                                                          \
  {                                                                          \
    float bi[8];                                                             \
    _Pragma("unroll")                                                        \
    for (int nf = 0; nf < 8; ++nf) bi[nf] = bias[nf * 16 + lr];              \
    int ho = h0 + 4 * (T) + ro;                                              \
    long long ob = ((long long)(n * HH + ho)) * WWID * F_OUT + lr;           \
    _Pragma("unroll")                                                        \
    for (int mfi = 0; mfi < 4; ++mfi) {                                      \
      _Pragma("unroll")                                                      \
      for (int r4 = 0; r4 < 4; ++r4) {                                       \
        int w = m0 + mfi * 16 + lg * 4 + r4;                                 \
        float* op = out + ob + (long long)w * F_OUT;                         \
        _Pragma("unroll")                                                    \
        for (int nf = 0; nf < 8; ++nf)                                       \
          op[nf * 16] = fmaxf(acc[mfi][nf][r4] + bi[nf], 0.f);               \
      }                                                                      \
    }                                                                        \
  }

  // ---- step 0 (rows h0..h0+3), with step-1 row loads pipelined in
  PREFETCH(1)
  COMPUTE(0, 0)
  __syncthreads();
  BWRITE()
  ISSUE_X(0)
  __syncthreads();
  PREFETCH(2)
  COMPUTE(0, 1)
  __syncthreads();
  BWRITE()
  DRAIN_X(0)
  ISSUE_X(1)
  __syncthreads();
  PREFETCH(0)
  COMPUTE(0, 2)
  __syncthreads();
  BWRITE()
  DRAIN_X(1)
  __syncthreads();
  PREFETCH(1)
  EPILOGUE(0)
#pragma unroll
  for (int mfi = 0; mfi < 4; ++mfi)
#pragma unroll
    for (int nf = 0; nf < 8; ++nf) acc[mfi][nf] = (f32x4){0.f, 0.f, 0.f, 0.f};

  // ---- step 1 (rows h0+4..h0+7)
  COMPUTE(1, 0)
  __syncthreads();
  BWRITE()
  __syncthreads();
  PREFETCH(2)
  COMPUTE(1, 1)
  __syncthreads();
  BWRITE()
  __syncthreads();
  COMPUTE(1, 2)
  EPILOGUE(1)

#undef PREFETCH
#undef BWRITE
#undef ISSUE_X
#undef DRAIN_X
#undef COMPUTE
#undef EPILOGUE
}

extern "C" void kernel_launch(void* const* d_in, const int* in_sizes, int n_in,
                              void* d_out, int out_size, void* d_ws, size_t ws_size,
                              hipStream_t stream) {
  const float* x    = (const float*)d_in[0];  // (16,128,128,64)
  const float* kern = (const float*)d_in[1];  // (3,3,64,128)
  const float* bias = (const float*)d_in[2];  // (128,)
  const float* D    = (const float*)d_in[3];  // (3,3,64,128)
  const float* gu   = (const float*)d_in[4];  // (1,128,64,9)

  unsigned short* AWsw = (unsigned short*)d_ws;  // 3 x 48 KiB = 144 KiB

  compute_aw<<<(F_OUT * C_IN + 255) / 256, 256, 0, stream>>>(kern, D, gu, AWsw);

  conv7<<<NB * (HH / 8), 512, 0, stream>>>(x, AWsw, bias, (float*)d_out);
}